// Round 5
// baseline (933.574 us; speedup 1.0000x reference)
//
#include <hip/hip_runtime.h>
#include <hip/hip_bf16.h>
#include <math.h>

#define B_N 16384
#define K_N 20
#define D_N 256
#define H_N 4

typedef __attribute__((ext_vector_type(8))) short v8s;
typedef __attribute__((ext_vector_type(4))) float v4f;
typedef __hip_bfloat16 bf16;

static __device__ __forceinline__ float bf2f(bf16 x){ return __bfloat162float(x); }
static __device__ __forceinline__ bf16 f2bf(float x){ return __float2bfloat16(x); }
static __device__ __forceinline__ float bfb2f(short s){ bf16 v; *(short*)&v = s; return __bfloat162float(v); }
static __device__ __forceinline__ short bfbits(float x){ bf16 v = __float2bfloat16(x); return *(short*)&v; }

// ---------------------------------------------------------------- prep ------
// builds all folded weights:
//  w1bT[k][j] = imp_w1[j][256+k]            (coalesced matvec operand)
//  wcat = [ad_w1(128); imp_w1[:, :256]]      + catb biases
//  g[h][d], qc[h]                            (q . bk folds)
//  Aw[c][e] = sum_i wq[h64+i][e] wk[h64+i][d]   (R = nm @ Aw + beta)
//  beta[c]  = sum_i bq[h64+i]   wk[h64+i][d]
//  Wm[i][k=h*256+d] = sum_jj wv[h64+jj][d] wout[i][h64+jj]  (agg = u @ Wm + cagg)
//  cagg[i]  = sum_j bv[j] wout[i][j] + bout[i]
//  nm_bf cast.
__global__ __launch_bounds__(256) void k_prep(
    const float* __restrict__ ad_w1, const float* __restrict__ ad_b1,
    const float* __restrict__ imp_w1, const float* __restrict__ imp_b1,
    const float* __restrict__ attn_in_w, const float* __restrict__ attn_in_b,
    const float* __restrict__ attn_out_w, const float* __restrict__ attn_out_b,
    const float* __restrict__ nm,
    bf16* __restrict__ w1bT, bf16* __restrict__ wcat, float* __restrict__ catb,
    float* __restrict__ g, float* __restrict__ qc,
    bf16* __restrict__ Aw, float* __restrict__ beta,
    bf16* __restrict__ Wm, float* __restrict__ cagg,
    bf16* __restrict__ nm_bf)
{
    long o = (long)blockIdx.x * 256 + threadIdx.x;
    const long n_w1bT = 65536, n_wcat = 384*256, n_catb = 384, n_g = 1024, n_qc = 4;
    const long n_Aw = 262144, n_beta = 1024, n_Wm = 262144, n_cagg = 256;
    const long n_nm = (long)B_N*256;
    if (o < n_w1bT){ // w1bT[k][j] = imp_w1[j][256+k]
        int k = (int)(o >> 8), j = (int)(o & 255);
        w1bT[o] = f2bf(imp_w1[j*512 + 256 + k]); return; } o -= n_w1bT;
    if (o < n_wcat){
        int r = (int)(o >> 8), c = (int)(o & 255); float v;
        if (r < 128) v = ad_w1[r*256 + c];
        else         v = imp_w1[(r-128)*512 + c];          // imp_w1[:, :256]
        wcat[o] = f2bf(v); return; } o -= n_wcat;
    if (o < n_catb){
        int r = (int)o;
        catb[r] = (r < 128) ? ad_b1[r] : imp_b1[r-128]; return; } o -= n_catb;
    if (o < n_g){   // g[h][d] = sum_i wq[h*64+i][d] * bk[h*64+i]
        int h = (int)(o >> 8), d = (int)(o & 255); float s = 0.f;
        for (int j = 0; j < 64; ++j) s += attn_in_w[(h*64+j)*256 + d] * attn_in_b[256 + h*64 + j];
        g[o] = s; return; } o -= n_g;
    if (o < n_qc){  // qc[h] = bq_h . bk_h
        int h = (int)o; float s = 0.f;
        for (int j = 0; j < 64; ++j) s += attn_in_b[h*64+j] * attn_in_b[256 + h*64 + j];
        qc[h] = s; return; } o -= n_qc;
    if (o < n_Aw){  // Aw[c][e], c = h*256+d
        int c = (int)(o >> 8), e = (int)(o & 255);
        int h = c >> 8, d = c & 255; float s = 0.f;
        for (int i = 0; i < 64; ++i)
            s += attn_in_w[(h*64+i)*256 + e] * attn_in_w[(256 + h*64 + i)*256 + d];
        Aw[o] = f2bf(s); return; } o -= n_Aw;
    if (o < n_beta){ // beta[c] = sum_i bq[h*64+i] * wk_h[i][d]
        int c = (int)o; int h = c >> 8, d = c & 255; float s = 0.f;
        for (int i = 0; i < 64; ++i)
            s += attn_in_b[h*64+i] * attn_in_w[(256 + h*64 + i)*256 + d];
        beta[c] = s; return; } o -= n_beta;
    if (o < n_Wm){  // Wm[i][k], k = h*256+d
        int i = (int)(o >> 10), k = (int)(o & 1023);
        int h = k >> 8, d = k & 255; float s = 0.f;
        for (int jj = 0; jj < 64; ++jj)
            s += attn_in_w[(512 + h*64 + jj)*256 + d] * attn_out_w[i*256 + h*64 + jj];
        Wm[o] = f2bf(s); return; } o -= n_Wm;
    if (o < n_cagg){ // cagg[i] = sum_j bv[j]*wout[i][j] + bout[i]
        int i = (int)o; float s = attn_out_b[i];
        for (int j = 0; j < 256; ++j) s += attn_in_b[512+j] * attn_out_w[i*256 + j];
        cagg[i] = s; return; } o -= n_cagg;
    if (o < n_nm){ nm_bf[o] = f2bf(nm[o]); return; }
}

// ---------------------------------------------------------------- gemm ------
// C[b][n] = epi( sum_k X[b][aoff+k] * W[n][k] + bias[n] + csrc[b][n] )
// 16x16x32 bf16 MFMA, block = 4 waves = 64 rows x 64 cols tile, no LDS.
__global__ __launch_bounds__(256) void k_gemm(
    const bf16* __restrict__ X, int ldx, int agshift, int agstride,
    const bf16* __restrict__ W, int ldw,
    const float* __restrict__ bias,
    const bf16* __restrict__ csrc, int ldc,
    void* __restrict__ outp, int ldo, int out_bf16,
    int relu_hi, int Kd)
{
    int wave = threadIdx.x >> 6, lane = threadIdx.x & 63;
    int l15 = lane & 15, koct = lane >> 4;
    int rblk = blockIdx.x * 64 + wave * 16;
    int cb = blockIdx.y * 64;
    long arow = rblk + l15;
    long aoff = (long)(cb >> agshift) * agstride;
    const bf16* Xp = X + arow * ldx + aoff + koct * 8;
    v4f acc[4];
    #pragma unroll
    for (int ct = 0; ct < 4; ++ct) acc[ct] = (v4f){0.f,0.f,0.f,0.f};
    for (int k0 = 0; k0 < Kd; k0 += 32){
        v8s a = *(const v8s*)(Xp + k0);
        #pragma unroll
        for (int ct = 0; ct < 4; ++ct){
            const bf16* Wp = W + (long)(cb + ct*16 + l15) * ldw + k0 + koct * 8;
            v8s bb = *(const v8s*)Wp;
            acc[ct] = __builtin_amdgcn_mfma_f32_16x16x32_bf16(a, bb, acc[ct], 0, 0, 0);
        }
    }
    int orow_base = rblk + koct * 4;   // C/D: row = (lane>>4)*4 + reg, col = lane&15
    #pragma unroll
    for (int ct = 0; ct < 4; ++ct){
        int ocol = cb + ct*16 + l15;
        float bv = bias ? bias[ocol] : 0.0f;
        #pragma unroll
        for (int r = 0; r < 4; ++r){
            long orow = orow_base + r;
            float v = acc[ct][r] + bv;
            if (csrc) v += bf2f(csrc[orow * ldc + ocol]);
            if (ocol < relu_hi) v = fmaxf(v, 0.0f);
            if (out_bf16) ((bf16*)outp)[orow * ldo + ocol] = f2bf(v);
            else          ((float*)outp)[orow * ldo + ocol] = v;
        }
    }
}

// ---------------------------------------------------------------- fused -----
// one block per batch, __launch_bounds__(256,6) -> 6 blocks/CU (LDS 25.7KB).
// Single storage pass: stats, coalesced wave-k-split matvec (w1bT), anomaly,
// importance, attention, st/u write. st rows 1..19 stream during staging.
// nm_s aliases redm[0:256] (dead before matvec writes redm; barrier-separated).
__global__ __launch_bounds__(256, 6) void k_fused(
    const float* __restrict__ storage, const float* __restrict__ nm,
    const bf16* __restrict__ R_bf, const bf16* __restrict__ cat1,
    const bf16* __restrict__ w1bT,
    const float* __restrict__ ad_w2, const float* __restrict__ ad_b2,
    const float* __restrict__ imp_w2, const float* __restrict__ imp_b2,
    const float* __restrict__ g, const float* __restrict__ qc,
    float* __restrict__ st_out, bf16* __restrict__ u_bf)
{
    __shared__ float4 stor4[K_N * 64];          // 20 rows x 64 float4 = 20480 B
    __shared__ float redm[4 * D_N];             // matvec partials; [0:256] doubles as nm_s
    __shared__ float mu_s[D_N];
    __shared__ float mask_s[K_N];
    __shared__ int   zc_s[H_N];
    __shared__ float red_s[2*H_N];              // [0..3] imp partials, [4..7] learned
    float* nm_s = redm;                         // alias (phase-disjoint)
    int b = blockIdx.x, t = threadIdx.x, h = t >> 6, lane = t & 63;
    const float4* S4 = (const float4*)(storage + (long)b * K_N * D_N);
    float4*       O4 = (float4*)(st_out + (long)b * K_N * D_N);

    float4 nm4 = ((const float4*)(nm + (long)b * D_N))[lane];

    // ---- staging: 20 rows, row mask via ballot, fused st rows 1..19 --------
    float4 vv[5];
    #pragma unroll
    for (int j = 0; j < 5; ++j) vv[j] = S4[t + j*256];   // row = h + 4j, col = lane
    if (h == 0) ((float4*)nm_s)[lane] = nm4;
    {
        float dd = 1.0f;
        #pragma unroll
        for (int j = 0; j < 3; ++j) if (j < h) dd *= 0.95f;   // 0.95^h
        const float step = 0.81450625f;                       // 0.95^4
        #pragma unroll
        for (int j = 0; j < 5; ++j){
            int i = t + j*256;
            int row = h + 4*j;
            stor4[i] = vv[j];
            bool nz = (vv[j].x != 0.f) || (vv[j].y != 0.f) || (vv[j].z != 0.f) || (vv[j].w != 0.f);
            unsigned long long bal = __ballot(nz);
            if (lane == 0) mask_s[row] = (bal != 0ULL) ? 1.0f : 0.0f;
            if (row < K_N-1){                      // st row (row+1) = storage[row]*0.95^row
                float4 o;
                o.x = vv[j].x * dd; o.y = vv[j].y * dd;
                o.z = vv[j].z * dd; o.w = vv[j].w * dd;
                O4[i + 64] = o;
            }
            dd *= step;
        }
    }
    __syncthreads();

    // ---- column stats: thread t = column d ---------------------------------
    {
        const float* S = (const float*)stor4;
        float cm = 0.f, s1 = 0.f, s2 = 0.f;
        #pragma unroll
        for (int k = 0; k < K_N; ++k){
            float m = mask_s[k];
            float x = S[k*D_N + t];
            cm += m; s1 += m*x; s2 += m*x*x;
        }
        float denom = cm + 1e-8f;
        float mu = s1 / denom;
        float var = (s2 - 2.0f*mu*s1 + mu*mu*cm) / denom;
        float sd = sqrtf(fmaxf(var, 0.0f));
        mu_s[t] = mu;
        float z = fabsf((nm_s[t] - mu) / (sd + 1e-8f));
        unsigned long long bal = __ballot(z > 2.0f);
        if (lane == 0) zc_s[h] = __popcll(bal);
    }
    __syncthreads();    // nm_s dead from here; redm writes begin

    // ---- coalesced matvec: wave h covers k in [64h, 64h+64) ----------------
    float pre1a = bf2f(cat1[(long)b*384 + 128 + t]);     // pre1a (incl imp_b1)
    {
        float ax = 0.f, ay = 0.f, az = 0.f, aw = 0.f;
        const bf16* wp = w1bT + (long)(h*64)*256 + 4*lane;
        #pragma unroll 4
        for (int s = 0; s < 64; ++s){
            ushort4 wv = *(const ushort4*)(wp + s*256);
            float m = mu_s[h*64 + s];
            ax += m * bfb2f((short)wv.x);
            ay += m * bfb2f((short)wv.y);
            az += m * bfb2f((short)wv.z);
            aw += m * bfb2f((short)wv.w);
        }
        float4 a4; a4.x = ax; a4.y = ay; a4.z = az; a4.w = aw;
        ((float4*)redm)[h*64 + lane] = a4;
    }
    __syncthreads();

    // ---- t[j] = relu(pre1a + sum_w redm); imp & learned partials -----------
    {
        float acc = pre1a + redm[t] + redm[256+t] + redm[512+t] + redm[768+t];
        float tj = fmaxf(acc, 0.0f);
        float pi = tj * imp_w2[t];
        float pl = (t < 128) ? bf2f(cat1[(long)b*384 + t]) * ad_w2[t] : 0.0f;
        #pragma unroll
        for (int s = 32; s; s >>= 1){ pi += __shfl_xor(pi, s); pl += __shfl_xor(pl, s); }
        if (lane == 0){ red_s[h] = pi; red_s[H_N + h] = pl; }
    }
    __syncthreads();

    float impv;
    {
        float p  = red_s[0]+red_s[1]+red_s[2]+red_s[3] + imp_b2[0];
        float plr= red_s[4]+red_s[5]+red_s[6]+red_s[7] + ad_b2[0];
        float learned = 1.0f / (1.0f + expf(-plr));
        float stat = (float)(zc_s[0]+zc_s[1]+zc_s[2]+zc_s[3]) * (1.0f/256.0f);
        float sp = (p > 20.0f) ? p : log1pf(expf(p));
        impv = sp * (1.0f + 0.5f*stat + 0.5f*learned);
    }
    if (h == 0){                              // st row 0 = imp * nm
        float4 o;
        o.x = impv * nm4.x; o.y = impv * nm4.y;
        o.z = impv * nm4.z; o.w = impv * nm4.w;
        O4[lane] = o;
    }

    // ---- scores: 21 partials, one batched shuffle reduce -------------------
    short4 r4  = ((const short4*)(R_bf + (long)b * (H_N*D_N) + h * D_N))[lane];
    float4 R4;
    R4.x = bfb2f(r4.x); R4.y = bfb2f(r4.y); R4.z = bfb2f(r4.z); R4.w = bfb2f(r4.w);
    float4 g4 = ((const float4*)(g + h * D_N))[lane];

    const int NP = K_N + 1;                   // [0]=nm.g, [1]=nm.R, [2+k]=row k.R
    float p[NP];
    p[0] = nm4.x*g4.x + nm4.y*g4.y + nm4.z*g4.z + nm4.w*g4.w;
    p[1] = nm4.x*R4.x + nm4.y*R4.y + nm4.z*R4.z + nm4.w*R4.w;
    #pragma unroll
    for (int k = 0; k < K_N-1; ++k){
        float4 x = stor4[k*64 + lane];
        p[2+k] = x.x*R4.x + x.y*R4.y + x.z*R4.z + x.w*R4.w;
    }
    #pragma unroll
    for (int s = 32; s; s >>= 1){
        #pragma unroll
        for (int j = 0; j < NP; ++j) p[j] += __shfl_xor(p[j], s);
    }
    float qb = p[0] + qc[h];
    float s0 = (impv * p[1] + qb) * 0.125f;   // in-place: p[2+k] -> score -> weight
    float mx = s0;
    {
        float dd = 1.0f;
        #pragma unroll
        for (int k = 0; k < K_N-1; ++k){
            p[2+k] = (dd * p[2+k] + qb) * 0.125f;
            mx = fmaxf(mx, p[2+k]);
            dd *= 0.95f;
        }
    }
    float w0 = expf(s0 - mx);
    float l = w0;
    #pragma unroll
    for (int k = 0; k < K_N-1; ++k){ p[2+k] = expf(p[2+k] - mx); l += p[2+k]; }
    float inv = 1.0f / l;
    w0 *= inv * impv;

    // ---- u = w0*nm + sum_k (p[2+k]*inv*dec_k)*storage[k] -------------------
    float4 acc;
    acc.x = w0 * nm4.x; acc.y = w0 * nm4.y; acc.z = w0 * nm4.z; acc.w = w0 * nm4.w;
    {
        float dd = inv;
        #pragma unroll
        for (int k = 0; k < K_N-1; ++k){
            float c = p[2+k] * dd;
            float4 x = stor4[k*64 + lane];
            acc.x += c*x.x; acc.y += c*x.y; acc.z += c*x.z; acc.w += c*x.w;
            dd *= 0.95f;
        }
    }
    short4 us;
    us.x = bfbits(acc.x); us.y = bfbits(acc.y); us.z = bfbits(acc.z); us.w = bfbits(acc.w);
    ((short4*)(u_bf + (long)b * (H_N*D_N) + h * D_N))[lane] = us;
}

// ---------------------------------------------------------------- launch ----
extern "C" void kernel_launch(void* const* d_in, const int* in_sizes, int n_in,
                              void* d_out, int out_size, void* d_ws, size_t ws_size,
                              hipStream_t stream)
{
    (void)in_sizes; (void)n_in; (void)out_size; (void)ws_size;
    const float* storage    = (const float*)d_in[0];
    const float* nm         = (const float*)d_in[1];
    const float* ad_w1      = (const float*)d_in[2];
    const float* ad_b1      = (const float*)d_in[3];
    const float* ad_w2      = (const float*)d_in[4];
    const float* ad_b2      = (const float*)d_in[5];
    const float* imp_w1     = (const float*)d_in[6];
    const float* imp_b1     = (const float*)d_in[7];
    const float* imp_w2     = (const float*)d_in[8];
    const float* imp_b2     = (const float*)d_in[9];
    const float* attn_in_w  = (const float*)d_in[10];
    const float* attn_in_b  = (const float*)d_in[11];
    const float* attn_out_w = (const float*)d_in[12];
    const float* attn_out_b = (const float*)d_in[13];

    char* p = (char*)d_ws;
    auto alloc = [&](size_t bytes)->char*{ char* r = p; p += (bytes + 255) & ~(size_t)255; return r; };
    bf16*  w1bT      = (bf16*) alloc((size_t)256*256*2);
    bf16*  wcat      = (bf16*) alloc((size_t)384*256*2);
    float* catb      = (float*)alloc((size_t)384*4);
    float* g         = (float*)alloc((size_t)1024*4);
    float* qc        = (float*)alloc((size_t)4*4);
    bf16*  Aw        = (bf16*) alloc((size_t)1024*256*2);
    float* beta      = (float*)alloc((size_t)1024*4);
    bf16*  Wm        = (bf16*) alloc((size_t)256*1024*2);
    float* cagg      = (float*)alloc((size_t)256*4);
    bf16*  nm_bf     = (bf16*) alloc((size_t)B_N*256*2);
    bf16*  cat1      = (bf16*) alloc((size_t)B_N*384*2);
    bf16*  R_bf      = (bf16*) alloc((size_t)B_N*1024*2);
    bf16*  u_bf      = (bf16*) alloc((size_t)B_N*1024*2);

    float* st_out  = (float*)d_out;
    float* agg_out = (float*)d_out + (size_t)B_N * K_N * D_N;

    // 1. prep (weight folds + casts)
    {
        long total = 65536 + 384*256 + 384 + 1024 + 4 + 262144 + 1024 + 262144 + 256 + (long)B_N*256;
        int grid = (int)((total + 255) / 256);
        k_prep<<<grid, 256, 0, stream>>>(ad_w1, ad_b1, imp_w1, imp_b1, attn_in_w, attn_in_b,
                                         attn_out_w, attn_out_b, nm,
                                         w1bT, wcat, catb, g, qc, Aw, beta, Wm, cagg, nm_bf);
    }
    // 2. cat1 = [relu(nm@ad_w1^T+ad_b1) | nm@imp_w1a^T+imp_b1]   (384 cols)
    k_gemm<<<dim3(B_N/64, 384/64), 256, 0, stream>>>(nm_bf, 256, 30, 0, wcat, 256, catb,
        (const bf16*)nullptr, 0, cat1, 384, 1, 128, 256);
    // 3. R = nm @ Aw + beta   (folded q@wk, K=256)
    k_gemm<<<dim3(B_N/64, 1024/64), 256, 0, stream>>>(nm_bf, 256, 30, 0, Aw, 256, beta,
        (const bf16*)nullptr, 0, R_bf, 1024, 1, 0, 256);
    // 4. fused stats + anomaly + importance + attention + st/u write
    k_fused<<<B_N, 256, 0, stream>>>(storage, nm, R_bf, cat1, w1bT,
        ad_w2, ad_b2, imp_w2, imp_b2, g, qc, st_out, u_bf);
    // 5. agg = u @ Wm + cagg   (folded wv+wout, K=1024, fp32 out)
    k_gemm<<<dim3(B_N/64, 256/64), 256, 0, stream>>>(u_bf, 1024, 30, 0, Wm, 1024, cagg,
        (const bf16*)nullptr, 0, agg_out, 256, 0, 0, 1024);
}

// Round 8
// 893.601 us; speedup vs baseline: 1.0447x; 1.0447x over previous
//
#include <hip/hip_runtime.h>
#include <hip/hip_bf16.h>
#include <math.h>

#define B_N 16384
#define K_N 20
#define D_N 256
#define H_N 4

typedef __attribute__((ext_vector_type(8))) short v8s;
typedef __attribute__((ext_vector_type(4))) float v4f;
typedef __hip_bfloat16 bf16;

static __device__ __forceinline__ float bf2f(bf16 x){ return __bfloat162float(x); }
static __device__ __forceinline__ bf16 f2bf(float x){ return __float2bfloat16(x); }
static __device__ __forceinline__ float bfb2f(short s){ bf16 v; *(short*)&v = s; return __bfloat162float(v); }
static __device__ __forceinline__ short bfbits(float x){ bf16 v = __float2bfloat16(x); return *(short*)&v; }
static __device__ __forceinline__ float4 bf4f(ushort4 a){
    float4 r; r.x = bfb2f((short)a.x); r.y = bfb2f((short)a.y);
    r.z = bfb2f((short)a.z); r.w = bfb2f((short)a.w); return r;
}
static __device__ __forceinline__ void nt_store4(float4 o, float4* p){
    v4f ov; ov[0] = o.x; ov[1] = o.y; ov[2] = o.z; ov[3] = o.w;
    __builtin_nontemporal_store(ov, (v4f*)p);
}

// ---------------------------------------------------------------- prep ------
// casts weights to bf16, builds Wcat=[ad_w1; wq; imp_w1a], catb, g_h, qc, wkT,
// w1bT (TRANSPOSED imp_w1[:,256:512] -> [k][j]), and nm_bf16.
__global__ __launch_bounds__(256) void k_prep(
    const float* __restrict__ ad_w1, const float* __restrict__ ad_b1,
    const float* __restrict__ imp_w1, const float* __restrict__ imp_b1,
    const float* __restrict__ attn_in_w, const float* __restrict__ attn_in_b,
    const float* __restrict__ attn_out_w, const float* __restrict__ nm,
    bf16* __restrict__ attn_bf, bf16* __restrict__ w1bT, bf16* __restrict__ wout_bf,
    bf16* __restrict__ wcat, float* __restrict__ catb,
    float* __restrict__ g, float* __restrict__ qc,
    bf16* __restrict__ wkT, bf16* __restrict__ nm_bf)
{
    long o = (long)blockIdx.x * 256 + threadIdx.x;
    const long n_attn = 768*256, n_w1b = 65536, n_wout = 256*256, n_wcat = 640*256;
    const long n_catb = 640, n_g = 1024, n_qc = 4, n_wkT = 1024*64, n_nm = (long)B_N*256;
    if (o < n_attn){ attn_bf[o] = f2bf(attn_in_w[o]); return; } o -= n_attn;
    if (o < n_w1b){ // w1bT[k][j] = imp_w1[j][256+k]  (transposed for coalesced matvec)
        int k = (int)(o >> 8), j = (int)(o & 255);
        w1bT[o] = f2bf(imp_w1[j*512 + 256 + k]); return; } o -= n_w1b;
    if (o < n_wout){ wout_bf[o] = f2bf(attn_out_w[o]); return; } o -= n_wout;
    if (o < n_wcat){
        int r = (int)(o >> 8), c = (int)(o & 255); float v;
        if (r < 128)      v = ad_w1[r*256 + c];
        else if (r < 384) v = attn_in_w[(r-128)*256 + c];       // wq rows
        else              v = imp_w1[(r-384)*512 + c];          // imp_w1[:, :256]
        wcat[o] = f2bf(v); return; } o -= n_wcat;
    if (o < n_catb){
        int r = (int)o; float v;
        if (r < 128) v = ad_b1[r]; else if (r < 384) v = attn_in_b[r-128]; else v = imp_b1[r-384];
        catb[r] = v; return; } o -= n_catb;
    if (o < n_g){   // g[h][d] = sum_i wq[h*64+i][d] * bk[h*64+i]
        int h = (int)(o >> 8), d = (int)(o & 255); float s = 0.f;
        for (int j = 0; j < 64; ++j) s += attn_in_w[(h*64+j)*256 + d] * attn_in_b[256 + h*64 + j];
        g[o] = s; return; } o -= n_g;
    if (o < n_qc){  // qc[h] = bq_h . bk_h
        int h = (int)o; float s = 0.f;
        for (int j = 0; j < 64; ++j) s += attn_in_b[h*64+j] * attn_in_b[256 + h*64 + j];
        qc[h] = s; return; } o -= n_qc;
    if (o < n_wkT){ // wkT[c][i] = wk[head(c)*64+i][d(c)],  c = h*256+d
        int c = (int)(o >> 6), i = (int)(o & 63);
        int h = c >> 8, d = c & 255;
        wkT[o] = f2bf(attn_in_w[(256 + h*64 + i)*256 + d]); return; } o -= n_wkT;
    if (o < n_nm){ nm_bf[o] = f2bf(nm[o]); return; }
}

// ---------------------------------------------------------------- gemm ------
// C[b][n] = epi( sum_k X[b][aoff+k] * W[n][k] + bias[n] + csrc[b][n] )
// 16x16x32 bf16 MFMA, block = 4 waves = 64 rows x 64 cols tile, no LDS.
__global__ __launch_bounds__(256) void k_gemm(
    const bf16* __restrict__ X, int ldx, int agshift, int agstride,
    const bf16* __restrict__ W, int ldw,
    const float* __restrict__ bias,
    const bf16* __restrict__ csrc, int ldc,
    void* __restrict__ outp, int ldo, int out_bf16,
    int relu_hi, int Kd)
{
    int wave = threadIdx.x >> 6, lane = threadIdx.x & 63;
    int l15 = lane & 15, koct = lane >> 4;
    int rblk = blockIdx.x * 64 + wave * 16;
    int cb = blockIdx.y * 64;
    long arow = rblk + l15;
    long aoff = (long)(cb >> agshift) * agstride;
    const bf16* Xp = X + arow * ldx + aoff + koct * 8;
    v4f acc[4];
    #pragma unroll
    for (int ct = 0; ct < 4; ++ct) acc[ct] = (v4f){0.f,0.f,0.f,0.f};
    for (int k0 = 0; k0 < Kd; k0 += 32){
        v8s a = *(const v8s*)(Xp + k0);
        #pragma unroll
        for (int ct = 0; ct < 4; ++ct){
            const bf16* Wp = W + (long)(cb + ct*16 + l15) * ldw + k0 + koct * 8;
            v8s bb = *(const v8s*)Wp;
            acc[ct] = __builtin_amdgcn_mfma_f32_16x16x32_bf16(a, bb, acc[ct], 0, 0, 0);
        }
    }
    int orow_base = rblk + koct * 4;   // C/D: row = (lane>>4)*4 + reg, col = lane&15
    #pragma unroll
    for (int ct = 0; ct < 4; ++ct){
        int ocol = cb + ct*16 + l15;
        float bv = bias ? bias[ocol] : 0.0f;
        #pragma unroll
        for (int r = 0; r < 4; ++r){
            long orow = orow_base + r;
            float v = acc[ct][r] + bv;
            if (csrc) v += bf2f(csrc[orow * ldc + ocol]);
            if (ocol < relu_hi) v = fmaxf(v, 0.0f);
            if (out_bf16) ((bf16*)outp)[orow * ldo + ocol] = f2bf(v);
            else          ((float*)outp)[orow * ldo + ocol] = v;
        }
    }
}

// ---------------------------------------------------------------- wave ------
// ONE WAVE per batch (4 batches per 256-thread block). All 20 storage rows
// live in registers (20 x float4 per lane, d = 4*lane..4*lane+3). Zero
// __syncthreads, zero stor LDS (only a 1KB/wave mu-exchange buffer).
// Computes: stats + z-count, w1b matvec (coalesced, L2-resident), learned +
// importance scalars, 4-head attention scores/softmax/u, st write (nt stores).
__global__ __launch_bounds__(256, 3) void k_wave(
    const float* __restrict__ storage, const float* __restrict__ nm,
    const bf16* __restrict__ R_bf, const bf16* __restrict__ cat1,
    const bf16* __restrict__ w1bT,
    const float* __restrict__ ad_w2, const float* __restrict__ ad_b2,
    const float* __restrict__ imp_w2, const float* __restrict__ imp_b2,
    const float* __restrict__ g, const float* __restrict__ qc,
    float* __restrict__ st_out, bf16* __restrict__ u_bf)
{
    __shared__ float mu_lds[4][D_N];            // per-wave mu exchange (4 KB)
    int w = threadIdx.x >> 6, lane = threadIdx.x & 63;
    long b = (long)blockIdx.x * 4 + w;
    const float4* S4 = (const float4*)(storage + b * K_N * D_N);
    float4*       O4 = (float4*)(st_out + b * K_N * D_N);

    // ---- load all rows + nm into registers ---------------------------------
    float4 rows[K_N];
    #pragma unroll
    for (int k = 0; k < K_N; ++k) rows[k] = S4[k*64 + lane];
    float4 nm4 = ((const float4*)(nm + b * D_N))[lane];

    // ---- masks (wave ballot), stats accum, fused st rows 1..19 (nt) --------
    float cm = 0.f;
    float4 s1 = {0.f,0.f,0.f,0.f}, s2 = {0.f,0.f,0.f,0.f};
    {
        float dd = 1.0f;
        #pragma unroll
        for (int k = 0; k < K_N; ++k){
            float4 x = rows[k];
            bool nz = (x.x != 0.f) || (x.y != 0.f) || (x.z != 0.f) || (x.w != 0.f);
            float m = (__ballot(nz) != 0ULL) ? 1.0f : 0.0f;
            cm += m;
            s1.x += m*x.x; s1.y += m*x.y; s1.z += m*x.z; s1.w += m*x.w;
            s2.x += m*x.x*x.x; s2.y += m*x.y*x.y; s2.z += m*x.z*x.z; s2.w += m*x.w*x.w;
            if (k < K_N-1){
                float4 o; o.x = x.x*dd; o.y = x.y*dd; o.z = x.z*dd; o.w = x.w*dd;
                nt_store4(o, &O4[(k+1)*64 + lane]);
            }
            dd *= 0.95f;
        }
    }
    float denom = cm + 1e-8f;
    float4 mu;
    mu.x = s1.x/denom; mu.y = s1.y/denom; mu.z = s1.z/denom; mu.w = s1.w/denom;
    float stat;
    {
        float vx = (s2.x - 2.f*mu.x*s1.x + mu.x*mu.x*cm)/denom;
        float vy = (s2.y - 2.f*mu.y*s1.y + mu.y*mu.y*cm)/denom;
        float vz = (s2.z - 2.f*mu.z*s1.z + mu.z*mu.z*cm)/denom;
        float vw = (s2.w - 2.f*mu.w*s1.w + mu.w*mu.w*cm)/denom;
        float sx = sqrtf(fmaxf(vx,0.f)) + 1e-8f, sy = sqrtf(fmaxf(vy,0.f)) + 1e-8f;
        float sz = sqrtf(fmaxf(vz,0.f)) + 1e-8f, sw = sqrtf(fmaxf(vw,0.f)) + 1e-8f;
        int zc = __popcll(__ballot(fabsf((nm4.x-mu.x)/sx) > 2.0f))
               + __popcll(__ballot(fabsf((nm4.y-mu.y)/sy) > 2.0f))
               + __popcll(__ballot(fabsf((nm4.z-mu.z)/sz) > 2.0f))
               + __popcll(__ballot(fabsf((nm4.w-mu.w)/sw) > 2.0f));
        stat = (float)zc * (1.0f/256.0f);
    }
    ((float4*)mu_lds[w])[lane] = mu;            // wave-coherent, no barrier

    // ---- matvec y[j] = sum_k mu[k]*w1bT[k][j], j = 4*lane.. (coalesced) ----
    float4 y = {0.f,0.f,0.f,0.f};
    {
        const bf16* wp = w1bT + 4*lane;
        #pragma unroll 4
        for (int k0 = 0; k0 < 64; ++k0){
            float4 m4 = ((const float4*)mu_lds[w])[k0];   // broadcast read
            float4 f0 = bf4f(*(const ushort4*)(wp + (4*k0+0)*256));
            float4 f1 = bf4f(*(const ushort4*)(wp + (4*k0+1)*256));
            float4 f2 = bf4f(*(const ushort4*)(wp + (4*k0+2)*256));
            float4 f3 = bf4f(*(const ushort4*)(wp + (4*k0+3)*256));
            y.x += m4.x*f0.x + m4.y*f1.x + m4.z*f2.x + m4.w*f3.x;
            y.y += m4.x*f0.y + m4.y*f1.y + m4.z*f2.y + m4.w*f3.y;
            y.z += m4.x*f0.z + m4.y*f1.z + m4.z*f2.z + m4.w*f3.z;
            y.w += m4.x*f0.w + m4.y*f1.w + m4.z*f2.w + m4.w*f3.w;
        }
    }

    // ---- t = relu(pre1a + y); imp + learned dots (batched reduce) ----------
    float impv;
    {
        short4 pr = ((const short4*)(cat1 + b*640 + 384))[lane];
        float4 w2 = ((const float4*)imp_w2)[lane];
        float tx = fmaxf(bfb2f(pr.x) + y.x, 0.f), ty = fmaxf(bfb2f(pr.y) + y.y, 0.f);
        float tz = fmaxf(bfb2f(pr.z) + y.z, 0.f), tw = fmaxf(bfb2f(pr.w) + y.w, 0.f);
        float pi = tx*w2.x + ty*w2.y + tz*w2.z + tw*w2.w;
        float pl = bf2f(cat1[b*640 + lane]) * ad_w2[lane]
                 + bf2f(cat1[b*640 + 64 + lane]) * ad_w2[64 + lane];
        #pragma unroll
        for (int s = 32; s; s >>= 1){ pi += __shfl_xor(pi, s); pl += __shfl_xor(pl, s); }
        float learned = 1.0f / (1.0f + expf(-(pl + ad_b2[0])));
        float pp = pi + imp_b2[0];
        float sp = (pp > 20.0f) ? pp : log1pf(expf(pp));
        impv = sp * (1.0f + 0.5f*stat + 0.5f*learned);
    }
    {   // st row 0 = imp * nm
        float4 o; o.x = impv*nm4.x; o.y = impv*nm4.y; o.z = impv*nm4.z; o.w = impv*nm4.w;
        nt_store4(o, &O4[lane]);
    }

    // ---- per-head scores / softmax / u (rows stay in registers) ------------
    const bf16* Rb = R_bf + b * (H_N*D_N);
    #pragma unroll 1
    for (int h = 0; h < H_N; ++h){
        short4 r4 = ((const short4*)(Rb + h*D_N))[lane];
        float4 R4 = bf4f(*(ushort4*)&r4);
        float4 g4 = ((const float4*)(g + h*D_N))[lane];
        float p[K_N+1];
        p[0] = nm4.x*g4.x + nm4.y*g4.y + nm4.z*g4.z + nm4.w*g4.w;
        p[1] = nm4.x*R4.x + nm4.y*R4.y + nm4.z*R4.z + nm4.w*R4.w;
        #pragma unroll
        for (int k = 0; k < K_N-1; ++k){
            float4 x = rows[k];
            p[2+k] = x.x*R4.x + x.y*R4.y + x.z*R4.z + x.w*R4.w;
        }
        #pragma unroll
        for (int s = 32; s; s >>= 1){
            #pragma unroll
            for (int j = 0; j < K_N+1; ++j) p[j] += __shfl_xor(p[j], s);
        }
        float qb = p[0] + qc[h];
        float s0 = (impv * p[1] + qb) * 0.125f;
        float mx = s0;
        {
            float dd = 1.0f;
            #pragma unroll
            for (int k = 0; k < K_N-1; ++k){
                p[2+k] = (dd * p[2+k] + qb) * 0.125f;
                mx = fmaxf(mx, p[2+k]);
                dd *= 0.95f;
            }
        }
        float w0 = __expf(s0 - mx);
        float l = w0;
        #pragma unroll
        for (int k = 0; k < K_N-1; ++k){ p[2+k] = __expf(p[2+k] - mx); l += p[2+k]; }
        float inv = 1.0f / l;
        w0 *= inv * impv;
        float4 acc;
        acc.x = w0*nm4.x; acc.y = w0*nm4.y; acc.z = w0*nm4.z; acc.w = w0*nm4.w;
        {
            float dd = inv;
            #pragma unroll
            for (int k = 0; k < K_N-1; ++k){
                float c = p[2+k] * dd;
                float4 x = rows[k];
                acc.x += c*x.x; acc.y += c*x.y; acc.z += c*x.z; acc.w += c*x.w;
                dd *= 0.95f;
            }
        }
        short4 us;
        us.x = bfbits(acc.x); us.y = bfbits(acc.y); us.z = bfbits(acc.z); us.w = bfbits(acc.w);
        ((short4*)(u_bf + b*(H_N*D_N) + h*D_N))[lane] = us;
    }
}

// ---------------------------------------------------------------- launch ----
extern "C" void kernel_launch(void* const* d_in, const int* in_sizes, int n_in,
                              void* d_out, int out_size, void* d_ws, size_t ws_size,
                              hipStream_t stream)
{
    (void)in_sizes; (void)n_in; (void)out_size; (void)ws_size;
    const float* storage    = (const float*)d_in[0];
    const float* nm         = (const float*)d_in[1];
    const float* ad_w1      = (const float*)d_in[2];
    const float* ad_b1      = (const float*)d_in[3];
    const float* ad_w2      = (const float*)d_in[4];
    const float* ad_b2      = (const float*)d_in[5];
    const float* imp_w1     = (const float*)d_in[6];
    const float* imp_b1     = (const float*)d_in[7];
    const float* imp_w2     = (const float*)d_in[8];
    const float* imp_b2     = (const float*)d_in[9];
    const float* attn_in_w  = (const float*)d_in[10];
    const float* attn_in_b  = (const float*)d_in[11];
    const float* attn_out_w = (const float*)d_in[12];
    const float* attn_out_b = (const float*)d_in[13];

    char* p = (char*)d_ws;
    auto alloc = [&](size_t bytes)->char*{ char* r = p; p += (bytes + 255) & ~(size_t)255; return r; };
    bf16*  attn_bf   = (bf16*) alloc((size_t)768*256*2);
    bf16*  w1bT      = (bf16*) alloc((size_t)256*256*2);
    bf16*  wout_bf   = (bf16*) alloc((size_t)256*256*2);
    bf16*  wcat      = (bf16*) alloc((size_t)640*256*2);
    float* catb      = (float*)alloc((size_t)640*4);
    float* g         = (float*)alloc((size_t)1024*4);
    float* qc        = (float*)alloc((size_t)4*4);
    bf16*  wkT       = (bf16*) alloc((size_t)1024*64*2);
    bf16*  nm_bf     = (bf16*) alloc((size_t)B_N*256*2);
    bf16*  cat1      = (bf16*) alloc((size_t)B_N*640*2);
    bf16*  R_bf      = (bf16*) alloc((size_t)B_N*1024*2);
    bf16*  u_bf      = (bf16*) alloc((size_t)B_N*1024*2);
    bf16*  ctx_bf    = (bf16*) alloc((size_t)B_N*256*2);

    float* st_out  = (float*)d_out;
    float* agg_out = (float*)d_out + (size_t)B_N * K_N * D_N;

    // 1. prep
    {
        long total = 768*256 + 65536 + 256*256 + 640*256 + 640 + 1024 + 4 + 1024*64 + (long)B_N*256;
        int grid = (int)((total + 255) / 256);
        k_prep<<<grid, 256, 0, stream>>>(ad_w1, ad_b1, imp_w1, imp_b1, attn_in_w, attn_in_b,
                                         attn_out_w, nm, attn_bf, w1bT, wout_bf, wcat, catb,
                                         g, qc, wkT, nm_bf);
    }
    // 2. fused nm GEMM: cols [0,128)=relu(ad) | [128,384)=q+bq | [384,640)=pre1a+imp_b1
    k_gemm<<<dim3(B_N/64, 640/64), 256, 0, stream>>>(nm_bf, 256, 30, 0, wcat, 256, catb,
        (const bf16*)nullptr, 0, cat1, 640, 1, 128, 256);
    // 3. R = q_h @ wk_h  (K=64, per-head A offset, wkT rows contiguous in k)
    k_gemm<<<dim3(B_N/64, 1024/64), 256, 0, stream>>>(cat1 + 128, 640, 8, 64, wkT, 64,
        (const float*)nullptr, (const bf16*)nullptr, 0, R_bf, 1024, 1, 0, 64);
    // 4. wave-per-batch fused stats + anomaly + importance + attention + st/u
    k_wave<<<B_N/4, 256, 0, stream>>>(storage, nm, R_bf, cat1, w1bT,
        ad_w2, ad_b2, imp_w2, imp_b2, g, qc, st_out, u_bf);
    // 5. ctx_head = u_head @ wv^T + bv   (per-64-col A group)
    k_gemm<<<dim3(B_N/64, 256/64), 256, 0, stream>>>(u_bf, 1024, 6, 256, attn_bf + 512*256, 256,
        attn_in_b + 512, (const bf16*)nullptr, 0, ctx_bf, 256, 1, 0, 256);
    // 6. agg = ctx @ Wout^T + bout  (fp32 out)
    k_gemm<<<dim3(B_N/64, 256/64), 256, 0, stream>>>(ctx_bf, 256, 30, 0, wout_bf, 256,
        attn_out_b, (const bf16*)nullptr, 0, agg_out, 256, 0, 0, 256);
}

// Round 9
// 850.744 us; speedup vs baseline: 1.0974x; 1.0504x over previous
//
#include <hip/hip_runtime.h>
#include <hip/hip_bf16.h>
#include <math.h>

#define B_N 16384
#define K_N 20
#define D_N 256
#define H_N 4

typedef __attribute__((ext_vector_type(8))) short v8s;
typedef __attribute__((ext_vector_type(4))) float v4f;
typedef __hip_bfloat16 bf16;

static __device__ __forceinline__ float bf2f(bf16 x){ return __bfloat162float(x); }
static __device__ __forceinline__ bf16 f2bf(float x){ return __float2bfloat16(x); }
static __device__ __forceinline__ float bfb2f(short s){ bf16 v; *(short*)&v = s; return __bfloat162float(v); }
static __device__ __forceinline__ short bfbits(float x){ bf16 v = __float2bfloat16(x); return *(short*)&v; }

// ---------------------------------------------------------------- prep ------
// casts weights to bf16, builds Wcat=[ad_w1; wq; imp_w1a], catb, g_h, qc, wkT,
// w1bT (TRANSPOSED imp_w1[:,256:512] -> [k][j]), and nm_bf16.
__global__ __launch_bounds__(256) void k_prep(
    const float* __restrict__ ad_w1, const float* __restrict__ ad_b1,
    const float* __restrict__ imp_w1, const float* __restrict__ imp_b1,
    const float* __restrict__ attn_in_w, const float* __restrict__ attn_in_b,
    const float* __restrict__ attn_out_w, const float* __restrict__ nm,
    bf16* __restrict__ attn_bf, bf16* __restrict__ w1bT, bf16* __restrict__ wout_bf,
    bf16* __restrict__ wcat, float* __restrict__ catb,
    float* __restrict__ g, float* __restrict__ qc,
    bf16* __restrict__ wkT, bf16* __restrict__ nm_bf)
{
    long o = (long)blockIdx.x * 256 + threadIdx.x;
    const long n_attn = 768*256, n_w1b = 65536, n_wout = 256*256, n_wcat = 640*256;
    const long n_catb = 640, n_g = 1024, n_qc = 4, n_wkT = 1024*64, n_nm = (long)B_N*256;
    if (o < n_attn){ attn_bf[o] = f2bf(attn_in_w[o]); return; } o -= n_attn;
    if (o < n_w1b){ // w1bT[k][j] = imp_w1[j][256+k]  (transposed for coalesced matvec)
        int k = (int)(o >> 8), j = (int)(o & 255);
        w1bT[o] = f2bf(imp_w1[j*512 + 256 + k]); return; } o -= n_w1b;
    if (o < n_wout){ wout_bf[o] = f2bf(attn_out_w[o]); return; } o -= n_wout;
    if (o < n_wcat){
        int r = (int)(o >> 8), c = (int)(o & 255); float v;
        if (r < 128)      v = ad_w1[r*256 + c];
        else if (r < 384) v = attn_in_w[(r-128)*256 + c];       // wq rows
        else              v = imp_w1[(r-384)*512 + c];          // imp_w1[:, :256]
        wcat[o] = f2bf(v); return; } o -= n_wcat;
    if (o < n_catb){
        int r = (int)o; float v;
        if (r < 128) v = ad_b1[r]; else if (r < 384) v = attn_in_b[r-128]; else v = imp_b1[r-384];
        catb[r] = v; return; } o -= n_catb;
    if (o < n_g){   // g[h][d] = sum_i wq[h*64+i][d] * bk[h*64+i]
        int h = (int)(o >> 8), d = (int)(o & 255); float s = 0.f;
        for (int j = 0; j < 64; ++j) s += attn_in_w[(h*64+j)*256 + d] * attn_in_b[256 + h*64 + j];
        g[o] = s; return; } o -= n_g;
    if (o < n_qc){  // qc[h] = bq_h . bk_h
        int h = (int)o; float s = 0.f;
        for (int j = 0; j < 64; ++j) s += attn_in_b[h*64+j] * attn_in_b[256 + h*64 + j];
        qc[h] = s; return; } o -= n_qc;
    if (o < n_wkT){ // wkT[c][i] = wk[head(c)*64+i][d(c)],  c = h*256+d
        int c = (int)(o >> 6), i = (int)(o & 63);
        int h = c >> 8, d = c & 255;
        wkT[o] = f2bf(attn_in_w[(256 + h*64 + i)*256 + d]); return; } o -= n_wkT;
    if (o < n_nm){ nm_bf[o] = f2bf(nm[o]); return; }
}

// ---------------------------------------------------------------- gemm ------
// C[b][n] = epi( sum_k X[b][aoff+k] * W[n][k] + bias[n] + csrc[b][n] )
// 16x16x32 bf16 MFMA, block = 4 waves = 64 rows x 64 cols tile, no LDS.
// (used only for g5 where the A-offset changes every 64 output cols)
__global__ __launch_bounds__(256) void k_gemm(
    const bf16* __restrict__ X, int ldx, int agshift, int agstride,
    const bf16* __restrict__ W, int ldw,
    const float* __restrict__ bias,
    const bf16* __restrict__ csrc, int ldc,
    void* __restrict__ outp, int ldo, int out_bf16,
    int relu_hi, int Kd)
{
    int wave = threadIdx.x >> 6, lane = threadIdx.x & 63;
    int l15 = lane & 15, koct = lane >> 4;
    int rblk = blockIdx.x * 64 + wave * 16;
    int cb = blockIdx.y * 64;
    long arow = rblk + l15;
    long aoff = (long)(cb >> agshift) * agstride;
    const bf16* Xp = X + arow * ldx + aoff + koct * 8;
    v4f acc[4];
    #pragma unroll
    for (int ct = 0; ct < 4; ++ct) acc[ct] = (v4f){0.f,0.f,0.f,0.f};
    for (int k0 = 0; k0 < Kd; k0 += 32){
        v8s a = *(const v8s*)(Xp + k0);
        #pragma unroll
        for (int ct = 0; ct < 4; ++ct){
            const bf16* Wp = W + (long)(cb + ct*16 + l15) * ldw + k0 + koct * 8;
            v8s bb = *(const v8s*)Wp;
            acc[ct] = __builtin_amdgcn_mfma_f32_16x16x32_bf16(a, bb, acc[ct], 0, 0, 0);
        }
    }
    int orow_base = rblk + koct * 4;   // C/D: row = (lane>>4)*4 + reg, col = lane&15
    #pragma unroll
    for (int ct = 0; ct < 4; ++ct){
        int ocol = cb + ct*16 + l15;
        float bv = bias ? bias[ocol] : 0.0f;
        #pragma unroll
        for (int r = 0; r < 4; ++r){
            long orow = orow_base + r;
            float v = acc[ct][r] + bv;
            if (csrc) v += bf2f(csrc[orow * ldc + ocol]);
            if (ocol < relu_hi) v = fmaxf(v, 0.0f);
            if (out_bf16) ((bf16*)outp)[orow * ldo + ocol] = f2bf(v);
            else          ((float*)outp)[orow * ldo + ocol] = v;
        }
    }
}

// ---------------------------------------------------------------- gemm2 -----
// 64 rows x 128 cols per block (4 waves x 8 col-fragments): 8 MFMA per A-load,
// 2x in-flight W loads, half the block count vs k_gemm. For head-aligned
// GEMMs (128 | head width). A-offset computed per tile (valid: 128 | 256).
__global__ __launch_bounds__(256) void k_gemm2(
    const bf16* __restrict__ X, int ldx, int agshift, int agstride,
    const bf16* __restrict__ W, int ldw,
    const float* __restrict__ bias,
    void* __restrict__ outp, int ldo, int out_bf16,
    int relu_hi, int Kd)
{
    int wave = threadIdx.x >> 6, lane = threadIdx.x & 63;
    int l15 = lane & 15, koct = lane >> 4;
    int rblk = blockIdx.x * 64 + wave * 16;
    int cb = blockIdx.y * 128;
    long arow = rblk + l15;
    long aoff = (long)(cb >> agshift) * agstride;
    const bf16* Xp = X + arow * ldx + aoff + koct * 8;
    v4f acc[8];
    #pragma unroll
    for (int ct = 0; ct < 8; ++ct) acc[ct] = (v4f){0.f,0.f,0.f,0.f};
    for (int k0 = 0; k0 < Kd; k0 += 32){
        v8s a = *(const v8s*)(Xp + k0);
        #pragma unroll
        for (int ct = 0; ct < 8; ++ct){
            const bf16* Wp = W + (long)(cb + ct*16 + l15) * ldw + k0 + koct * 8;
            v8s bb = *(const v8s*)Wp;
            acc[ct] = __builtin_amdgcn_mfma_f32_16x16x32_bf16(a, bb, acc[ct], 0, 0, 0);
        }
    }
    int orow_base = rblk + koct * 4;
    #pragma unroll
    for (int ct = 0; ct < 8; ++ct){
        int ocol = cb + ct*16 + l15;
        float bv = bias ? bias[ocol] : 0.0f;
        #pragma unroll
        for (int r = 0; r < 4; ++r){
            long orow = orow_base + r;
            float v = acc[ct][r] + bv;
            if (ocol < relu_hi) v = fmaxf(v, 0.0f);
            if (out_bf16) ((bf16*)outp)[orow * ldo + ocol] = f2bf(v);
            else          ((float*)outp)[orow * ldo + ocol] = v;
        }
    }
}

// ---------------------------------------------------------------- fused -----
// one block per batch, __launch_bounds__(256,6) -> 6 blocks/CU (LDS 25.7KB).
// Single storage pass: stats, coalesced wave-k-split matvec (w1bT), anomaly,
// importance, attention, st/u write. st rows 1..19 stream during staging.
// nm_s aliases redm[0:256] (dead/live ranges barrier-separated).
__global__ __launch_bounds__(256, 6) void k_fused(
    const float* __restrict__ storage, const float* __restrict__ nm,
    const bf16* __restrict__ R_bf, const bf16* __restrict__ cat1,
    const bf16* __restrict__ w1bT,
    const float* __restrict__ ad_w2, const float* __restrict__ ad_b2,
    const float* __restrict__ imp_w2, const float* __restrict__ imp_b2,
    const float* __restrict__ g, const float* __restrict__ qc,
    float* __restrict__ st_out, bf16* __restrict__ u_bf)
{
    __shared__ float4 stor4[K_N * 64];          // 20 rows x 64 float4 = 20480 B
    __shared__ float redm[4 * D_N];             // matvec partials; [0:256] doubles as nm_s
    __shared__ float mu_s[D_N];
    __shared__ float mask_s[K_N];
    __shared__ int   zc_s[H_N];
    __shared__ float red_s[2*H_N];              // [0..3] imp partials, [4..7] learned
    float* nm_s = redm;                         // alias (phase-disjoint)
    int b = blockIdx.x, t = threadIdx.x, h = t >> 6, lane = t & 63;
    const float4* S4 = (const float4*)(storage + (long)b * K_N * D_N);
    float4*       O4 = (float4*)(st_out + (long)b * K_N * D_N);

    float4 nm4 = ((const float4*)(nm + (long)b * D_N))[lane];

    // ---- staging: 20 rows, row mask via ballot, fused st rows 1..19 --------
    float4 vv[5];
    #pragma unroll
    for (int j = 0; j < 5; ++j) vv[j] = S4[t + j*256];   // row = h + 4j, col = lane
    if (h == 0) ((float4*)nm_s)[lane] = nm4;
    {
        float dd = 1.0f;
        #pragma unroll
        for (int j = 0; j < 3; ++j) if (j < h) dd *= 0.95f;   // 0.95^h
        const float step = 0.81450625f;                       // 0.95^4
        #pragma unroll
        for (int j = 0; j < 5; ++j){
            int i = t + j*256;
            int row = h + 4*j;
            stor4[i] = vv[j];
            bool nz = (vv[j].x != 0.f) || (vv[j].y != 0.f) || (vv[j].z != 0.f) || (vv[j].w != 0.f);
            unsigned long long bal = __ballot(nz);
            if (lane == 0) mask_s[row] = (bal != 0ULL) ? 1.0f : 0.0f;
            if (row < K_N-1){                      // st row (row+1) = storage[row]*0.95^row
                float4 o;
                o.x = vv[j].x * dd; o.y = vv[j].y * dd;
                o.z = vv[j].z * dd; o.w = vv[j].w * dd;
                O4[i + 64] = o;
            }
            dd *= step;
        }
    }
    __syncthreads();

    // ---- column stats: thread t = column d ---------------------------------
    {
        const float* S = (const float*)stor4;
        float cm = 0.f, s1 = 0.f, s2 = 0.f;
        #pragma unroll
        for (int k = 0; k < K_N; ++k){
            float m = mask_s[k];
            float x = S[k*D_N + t];
            cm += m; s1 += m*x; s2 += m*x*x;
        }
        float denom = cm + 1e-8f;
        float mu = s1 / denom;
        float var = (s2 - 2.0f*mu*s1 + mu*mu*cm) / denom;
        float sd = sqrtf(fmaxf(var, 0.0f));
        mu_s[t] = mu;
        float z = fabsf((nm_s[t] - mu) / (sd + 1e-8f));
        unsigned long long bal = __ballot(z > 2.0f);
        if (lane == 0) zc_s[h] = __popcll(bal);
    }
    __syncthreads();    // nm_s dead from here; redm writes begin

    // ---- coalesced matvec: wave h covers k in [64h, 64h+64) ----------------
    float pre1a = bf2f(cat1[(long)b*640 + 384 + t]);     // pre1a (incl imp_b1)
    {
        float ax = 0.f, ay = 0.f, az = 0.f, aw = 0.f;
        const bf16* wp = w1bT + (long)(h*64)*256 + 4*lane;
        #pragma unroll 4
        for (int s = 0; s < 64; ++s){
            ushort4 wv = *(const ushort4*)(wp + s*256);
            float m = mu_s[h*64 + s];
            ax += m * bfb2f((short)wv.x);
            ay += m * bfb2f((short)wv.y);
            az += m * bfb2f((short)wv.z);
            aw += m * bfb2f((short)wv.w);
        }
        float4 a4; a4.x = ax; a4.y = ay; a4.z = az; a4.w = aw;
        ((float4*)redm)[h*64 + lane] = a4;
    }
    __syncthreads();

    // ---- t[j] = relu(pre1a + sum_w redm); imp & learned partials -----------
    {
        float acc = pre1a + redm[t] + redm[256+t] + redm[512+t] + redm[768+t];
        float tj = fmaxf(acc, 0.0f);
        float pi = tj * imp_w2[t];
        float pl = (t < 128) ? bf2f(cat1[(long)b*640 + t]) * ad_w2[t] : 0.0f;
        #pragma unroll
        for (int s = 32; s; s >>= 1){ pi += __shfl_xor(pi, s); pl += __shfl_xor(pl, s); }
        if (lane == 0){ red_s[h] = pi; red_s[H_N + h] = pl; }
    }
    __syncthreads();

    float impv;
    {
        float p  = red_s[0]+red_s[1]+red_s[2]+red_s[3] + imp_b2[0];
        float plr= red_s[4]+red_s[5]+red_s[6]+red_s[7] + ad_b2[0];
        float learned = 1.0f / (1.0f + expf(-plr));
        float stat = (float)(zc_s[0]+zc_s[1]+zc_s[2]+zc_s[3]) * (1.0f/256.0f);
        float sp = (p > 20.0f) ? p : log1pf(expf(p));
        impv = sp * (1.0f + 0.5f*stat + 0.5f*learned);
    }
    if (h == 0){                              // st row 0 = imp * nm
        float4 o;
        o.x = impv * nm4.x; o.y = impv * nm4.y;
        o.z = impv * nm4.z; o.w = impv * nm4.w;
        O4[lane] = o;
    }

    // ---- scores: 21 partials, one batched shuffle reduce -------------------
    short4 r4  = ((const short4*)(R_bf + (long)b * (H_N*D_N) + h * D_N))[lane];
    float4 R4;
    R4.x = bfb2f(r4.x); R4.y = bfb2f(r4.y); R4.z = bfb2f(r4.z); R4.w = bfb2f(r4.w);
    float4 g4 = ((const float4*)(g + h * D_N))[lane];

    const int NP = K_N + 1;                   // [0]=nm.g, [1]=nm.R, [2+k]=row k.R
    float p[NP];
    p[0] = nm4.x*g4.x + nm4.y*g4.y + nm4.z*g4.z + nm4.w*g4.w;
    p[1] = nm4.x*R4.x + nm4.y*R4.y + nm4.z*R4.z + nm4.w*R4.w;
    #pragma unroll
    for (int k = 0; k < K_N-1; ++k){
        float4 x = stor4[k*64 + lane];
        p[2+k] = x.x*R4.x + x.y*R4.y + x.z*R4.z + x.w*R4.w;
    }
    #pragma unroll
    for (int s = 32; s; s >>= 1){
        #pragma unroll
        for (int j = 0; j < NP; ++j) p[j] += __shfl_xor(p[j], s);
    }
    float qb = p[0] + qc[h];
    float s0 = (impv * p[1] + qb) * 0.125f;   // in-place: p[2+k] -> score -> weight
    float mx = s0;
    {
        float dd = 1.0f;
        #pragma unroll
        for (int k = 0; k < K_N-1; ++k){
            p[2+k] = (dd * p[2+k] + qb) * 0.125f;
            mx = fmaxf(mx, p[2+k]);
            dd *= 0.95f;
        }
    }
    float w0 = expf(s0 - mx);
    float l = w0;
    #pragma unroll
    for (int k = 0; k < K_N-1; ++k){ p[2+k] = expf(p[2+k] - mx); l += p[2+k]; }
    float inv = 1.0f / l;
    w0 *= inv * impv;

    // ---- u = w0*nm + sum_k (p[2+k]*inv*dec_k)*storage[k] -------------------
    float4 acc;
    acc.x = w0 * nm4.x; acc.y = w0 * nm4.y; acc.z = w0 * nm4.z; acc.w = w0 * nm4.w;
    {
        float dd = inv;
        #pragma unroll
        for (int k = 0; k < K_N-1; ++k){
            float c = p[2+k] * dd;
            float4 x = stor4[k*64 + lane];
            acc.x += c*x.x; acc.y += c*x.y; acc.z += c*x.z; acc.w += c*x.w;
            dd *= 0.95f;
        }
    }
    short4 us;
    us.x = bfbits(acc.x); us.y = bfbits(acc.y); us.z = bfbits(acc.z); us.w = bfbits(acc.w);
    ((short4*)(u_bf + (long)b * (H_N*D_N) + h * D_N))[lane] = us;
}

// ---------------------------------------------------------------- launch ----
extern "C" void kernel_launch(void* const* d_in, const int* in_sizes, int n_in,
                              void* d_out, int out_size, void* d_ws, size_t ws_size,
                              hipStream_t stream)
{
    (void)in_sizes; (void)n_in; (void)out_size; (void)ws_size;
    const float* storage    = (const float*)d_in[0];
    const float* nm         = (const float*)d_in[1];
    const float* ad_w1      = (const float*)d_in[2];
    const float* ad_b1      = (const float*)d_in[3];
    const float* ad_w2      = (const float*)d_in[4];
    const float* ad_b2      = (const float*)d_in[5];
    const float* imp_w1     = (const float*)d_in[6];
    const float* imp_b1     = (const float*)d_in[7];
    const float* imp_w2     = (const float*)d_in[8];
    const float* imp_b2     = (const float*)d_in[9];
    const float* attn_in_w  = (const float*)d_in[10];
    const float* attn_in_b  = (const float*)d_in[11];
    const float* attn_out_w = (const float*)d_in[12];
    const float* attn_out_b = (const float*)d_in[13];

    char* p = (char*)d_ws;
    auto alloc = [&](size_t bytes)->char*{ char* r = p; p += (bytes + 255) & ~(size_t)255; return r; };
    bf16*  attn_bf   = (bf16*) alloc((size_t)768*256*2);
    bf16*  w1bT      = (bf16*) alloc((size_t)256*256*2);
    bf16*  wout_bf   = (bf16*) alloc((size_t)256*256*2);
    bf16*  wcat      = (bf16*) alloc((size_t)640*256*2);
    float* catb      = (float*)alloc((size_t)640*4);
    float* g         = (float*)alloc((size_t)1024*4);
    float* qc        = (float*)alloc((size_t)4*4);
    bf16*  wkT       = (bf16*) alloc((size_t)1024*64*2);
    bf16*  nm_bf     = (bf16*) alloc((size_t)B_N*256*2);
    bf16*  cat1      = (bf16*) alloc((size_t)B_N*640*2);
    bf16*  R_bf      = (bf16*) alloc((size_t)B_N*1024*2);
    bf16*  u_bf      = (bf16*) alloc((size_t)B_N*1024*2);
    bf16*  ctx_bf    = (bf16*) alloc((size_t)B_N*256*2);

    float* st_out  = (float*)d_out;
    float* agg_out = (float*)d_out + (size_t)B_N * K_N * D_N;

    // 1. prep
    {
        long total = 768*256 + 65536 + 256*256 + 640*256 + 640 + 1024 + 4 + 1024*64 + (long)B_N*256;
        int grid = (int)((total + 255) / 256);
        k_prep<<<grid, 256, 0, stream>>>(ad_w1, ad_b1, imp_w1, imp_b1, attn_in_w, attn_in_b,
                                         attn_out_w, nm, attn_bf, w1bT, wout_bf, wcat, catb,
                                         g, qc, wkT, nm_bf);
    }
    // 2. fused nm GEMM (64x128 tiles): [0,128)=relu(ad) | [128,384)=q+bq | [384,640)=pre1a
    k_gemm2<<<dim3(B_N/64, 640/128), 256, 0, stream>>>(nm_bf, 256, 30, 0, wcat, 256, catb,
        cat1, 640, 1, 128, 256);
    // 3. R = q_h @ wk_h  (K=64, per-head A offset; 128 | 256 so tiles head-aligned)
    k_gemm2<<<dim3(B_N/64, 1024/128), 256, 0, stream>>>(cat1 + 128, 640, 8, 64, wkT, 64,
        (const float*)nullptr, R_bf, 1024, 1, 0, 64);
    // 4. fused stats + anomaly + importance + attention + st/u write
    k_fused<<<B_N, 256, 0, stream>>>(storage, nm, R_bf, cat1, w1bT,
        ad_w2, ad_b2, imp_w2, imp_b2, g, qc, st_out, u_bf);
    // 5. ctx_head = u_head @ wv^T + bv  (A-offset per 64 cols -> keep 64-wide kernel)
    k_gemm<<<dim3(B_N/64, 256/64), 256, 0, stream>>>(u_bf, 1024, 6, 256, attn_bf + 512*256, 256,
        attn_in_b + 512, (const bf16*)nullptr, 0, ctx_bf, 256, 1, 0, 256);
    // 6. agg = ctx @ Wout^T + bout  (fp32 out, 64x128 tiles)
    k_gemm2<<<dim3(B_N/64, 256/128), 256, 0, stream>>>(ctx_bf, 256, 30, 0, wout_bf, 256,
        attn_out_b, agg_out, 256, 0, 0, 256);
}